// Round 3
// baseline (857.017 us; speedup 1.0000x reference)
//
#include <hip/hip_runtime.h>

// Problem constants (reference: N=2048, H=2048, V=32000)
#define MDIM 2048
#define KDIM 2048
#define VDIM 32000
#define BM 256
#define BN 256
#define BK 64
#define NT (KDIM / BK)   // 32 K-tiles
#define LDAB (2 * KDIM)  // bf16 row stride inside the in-place-cast fp32 buffer

typedef __bf16 bf16x8 __attribute__((ext_vector_type(8)));
typedef float f32x16 __attribute__((ext_vector_type(16)));

__device__ __forceinline__ unsigned short f32_to_bf16_rne(float f) {
    unsigned u = __float_as_uint(f);
    u += 0x7FFFu + ((u >> 16) & 1u);
    return (unsigned short)(u >> 16);
}

// In-place fp32 -> bf16 row compaction, 4 rows per block (unchanged, proven).
__global__ __launch_bounds__(256) void cast_inplace_rows4_kernel(
        float* __restrict__ rows, float* zero_out) {
    if (zero_out && blockIdx.x == 0 && threadIdx.x == 0) *zero_out = 0.0f;
    float* base = rows + (long)blockIdx.x * 4 * KDIM;
    const int t = threadIdx.x;
    float4 v[8];
#pragma unroll
    for (int rr = 0; rr < 4; ++rr) {
        const float4* p = reinterpret_cast<const float4*>(base + rr * KDIM + t * 8);
        v[2 * rr]     = p[0];
        v[2 * rr + 1] = p[1];
    }
    __syncthreads();
#pragma unroll
    for (int rr = 0; rr < 4; ++rr) {
        union { unsigned short h[8]; uint4 u; } r;
        float4 a = v[2 * rr], b = v[2 * rr + 1];
        r.h[0] = f32_to_bf16_rne(a.x);
        r.h[1] = f32_to_bf16_rne(a.y);
        r.h[2] = f32_to_bf16_rne(a.z);
        r.h[3] = f32_to_bf16_rne(a.w);
        r.h[4] = f32_to_bf16_rne(b.x);
        r.h[5] = f32_to_bf16_rne(b.y);
        r.h[6] = f32_to_bf16_rne(b.z);
        r.h[7] = f32_to_bf16_rne(b.w);
        reinterpret_cast<uint4*>(base + rr * KDIM)[t] = r.u;
    }
}

// ---------------------------------------------------------------------------
// 256x256 tile, 4 waves (1/SIMD), per-wave 128x128, mfma_f32_32x32x16_bf16.
// Register-pipelined k-steps (frags for k+1 read during k's MFMA, counted
// lgkmcnt(8)); ONE vmcnt(0)+s_barrier per K-tile, with all 16 staging DMAs
// issued at tile start (~2000 cy to land -> drain nearly free).
// LDS: As[2][256*64] + Bs[2][256*64] bf16 = 128 KiB double-buffered.
// XOR swizzle (0 conflicts measured): row r stores global 16B-seg g at slot
// g ^ (r&7); readers XOR likewise.
// 32x32x16 layouts: A/B operand: row(col)=lane&31, k = (lane>>5)*8 + 0..7
// (generalizes the session-verified 16x16x32 mapping). C/D (doc-verified
// m74/m101): col=lane&31 (SECOND operand dim), row=(reg&3)+8*(reg>>2)+
// 4*(lane>>5) (FIRST operand dim). We pass W-frag FIRST so each lane's
// reg-quads span 4 CONSECUTIVE V columns -> float4 Y loads in the epilogue.
// ---------------------------------------------------------------------------

#define MFMA3216(a, b, c) __builtin_amdgcn_mfma_f32_32x32x16_bf16(a, b, c, 0, 0, 0)

#define GLL16(gp, lp) __builtin_amdgcn_global_load_lds( \
    (const __attribute__((address_space(1))) void*)(gp), \
    (__attribute__((address_space(3))) void*)(lp), 16, 0, 0)

// 16 DMA ops per thread: full next tile (A 32 KB + B 32 KB).
#define STAGE(bi, kt) do { \
    _Pragma("unroll") \
    for (int s_ = 0; s_ < 8; ++s_) { \
        GLL16(aG + (size_t)32 * s_ * LDAB + (kt), &As[(bi)][tid8 + 2048 * s_]); \
        GLL16(bG + (size_t)32 * s_ * LDAB + (kt), &Bs[(bi)][tid8 + 2048 * s_]); \
    } \
} while (0)

// Stored 16B-seg for (k-step ks, k-half kh) at row with row&7 == lane&7.
#define SGO(ks) ((((2 * (ks)) + kh) ^ xorv) * 8)

// 8 ds_read_b128: A frags m=0..3, B frags n=0..3 for k-step ks.
#define RDF(bi, ks, AF, BF) do { \
    const unsigned short* aB_ = &As[(bi)][rowA * BK]; \
    const unsigned short* bB_ = &Bs[(bi)][rowB * BK]; \
    AF[0] = *(const bf16x8*)(const void*)(aB_ + SGO(ks)); \
    AF[1] = *(const bf16x8*)(const void*)(aB_ + 32 * BK + SGO(ks)); \
    AF[2] = *(const bf16x8*)(const void*)(aB_ + 64 * BK + SGO(ks)); \
    AF[3] = *(const bf16x8*)(const void*)(aB_ + 96 * BK + SGO(ks)); \
    BF[0] = *(const bf16x8*)(const void*)(bB_ + SGO(ks)); \
    BF[1] = *(const bf16x8*)(const void*)(bB_ + 32 * BK + SGO(ks)); \
    BF[2] = *(const bf16x8*)(const void*)(bB_ + 64 * BK + SGO(ks)); \
    BF[3] = *(const bf16x8*)(const void*)(bB_ + 96 * BK + SGO(ks)); \
} while (0)

// 16 independent MFMAs (W-frag FIRST operand).
#define MM16(AF, BF) do { \
    acc[0][0] = MFMA3216(BF[0], AF[0], acc[0][0]); \
    acc[0][1] = MFMA3216(BF[1], AF[0], acc[0][1]); \
    acc[0][2] = MFMA3216(BF[2], AF[0], acc[0][2]); \
    acc[0][3] = MFMA3216(BF[3], AF[0], acc[0][3]); \
    acc[1][0] = MFMA3216(BF[0], AF[1], acc[1][0]); \
    acc[1][1] = MFMA3216(BF[1], AF[1], acc[1][1]); \
    acc[1][2] = MFMA3216(BF[2], AF[1], acc[1][2]); \
    acc[1][3] = MFMA3216(BF[3], AF[1], acc[1][3]); \
    acc[2][0] = MFMA3216(BF[0], AF[2], acc[2][0]); \
    acc[2][1] = MFMA3216(BF[1], AF[2], acc[2][1]); \
    acc[2][2] = MFMA3216(BF[2], AF[2], acc[2][2]); \
    acc[2][3] = MFMA3216(BF[3], AF[2], acc[2][3]); \
    acc[3][0] = MFMA3216(BF[0], AF[3], acc[3][0]); \
    acc[3][1] = MFMA3216(BF[1], AF[3], acc[3][1]); \
    acc[3][2] = MFMA3216(BF[2], AF[3], acc[3][2]); \
    acc[3][3] = MFMA3216(BF[3], AF[3], acc[3][3]); \
} while (0)

#define SCHEDB() __builtin_amdgcn_sched_barrier(0)
#define LGKM(n)  do { asm volatile("s_waitcnt lgkmcnt(" #n ")" ::: "memory"); SCHEDB(); } while (0)
#define VM0()    do { asm volatile("s_waitcnt vmcnt(0)" ::: "memory"); SCHEDB(); } while (0)

// One K-tile: read k0, stage next tile, pipelined 4 k-steps, drain, barrier.
#define KTILE(bi, ktN) do { \
    RDF(bi, 0, af0, bf0); \
    STAGE((bi) ^ 1, ktN); \
    RDF(bi, 1, af1, bf1); \
    LGKM(8); \
    __builtin_amdgcn_s_setprio(1); MM16(af0, bf0); __builtin_amdgcn_s_setprio(0); \
    RDF(bi, 2, af0, bf0); \
    LGKM(8); \
    __builtin_amdgcn_s_setprio(1); MM16(af1, bf1); __builtin_amdgcn_s_setprio(0); \
    RDF(bi, 3, af1, bf1); \
    LGKM(8); \
    __builtin_amdgcn_s_setprio(1); MM16(af0, bf0); __builtin_amdgcn_s_setprio(0); \
    LGKM(0); \
    __builtin_amdgcn_s_setprio(1); MM16(af1, bf1); __builtin_amdgcn_s_setprio(0); \
    VM0(); \
    __builtin_amdgcn_s_barrier(); SCHEDB(); \
} while (0)

__global__ __launch_bounds__(256, 1) void gemm_mse_kernel(
        const unsigned short* __restrict__ A,  // x as bf16, stride LDAB
        const unsigned short* __restrict__ B,  // W as bf16, stride LDAB
        const float* __restrict__ Y,           // [MDIM,VDIM] fp32
        float* __restrict__ out) {
    __shared__ __align__(16) unsigned short As[2][BM * BK];  // 64 KB
    __shared__ __align__(16) unsigned short Bs[2][BN * BK];  // 64 KB

    const int tid  = threadIdx.x;
    const int lane = tid & 63;
    const int wid  = tid >> 6;            // 0..3
    const int wrow = (wid >> 1) * 128;    // wave M offset in tile
    const int wcol = (wid & 1) * 128;     // wave V offset in tile
    const int l31  = lane & 31;
    const int kh   = lane >> 5;           // k-half 0/1
    const int xorv = lane & 7;            // == row&7 for all fragment rows

    // XCD-aware bijective swizzle: 1000 blocks, 1000 % 8 == 0.
    const int lin = blockIdx.x;
    const int swz = (lin & 7) * 125 + (lin >> 3);
    const int tm = swz & 7;               // 8 M tiles (fast)
    const int tv = swz >> 3;              // 125 V tiles (slow)
    const long rowBase = (long)tm * BM;
    const long colBase = (long)tv * BN;

    f32x16 acc[4][4];
    {
        const f32x16 z = {0.f,0.f,0.f,0.f,0.f,0.f,0.f,0.f,
                          0.f,0.f,0.f,0.f,0.f,0.f,0.f,0.f};
#pragma unroll
        for (int m = 0; m < 4; ++m)
#pragma unroll
            for (int n = 0; n < 4; ++n)
                acc[m][n] = z;
    }

    // Staging addressing: tile = 256 rows x 64 bf16 (per matrix) = 2048 slots
    // of 16B; 256 threads x 8 slots. Slot l = tid + 256*s: row = l>>3 =
    // (tid>>3)+32s, stored seg = l&7 = tid&7, global seg g = (tid&7)^(row&7);
    // row&7 == (tid>>3)&7 (32s = 0 mod 8) -> g uniform across s: ONE base ptr.
    const int srow = tid >> 3;
    const int g0   = (tid & 7) ^ (srow & 7);
    const unsigned short* aG = A + (size_t)(rowBase + srow) * LDAB + g0 * 8;
    const unsigned short* bG = B + (size_t)(colBase + srow) * LDAB + g0 * 8;
    const int tid8 = tid * 8;             // LDS offset (shorts) of slot s=0

    const int rowA = wrow + l31;          // + m*32 per fragment
    const int rowB = wcol + l31;          // + n*32 per fragment

    bf16x8 af0[4], bf0[4], af1[4], bf1[4];

    // Prologue: stage T0 into buf0, drain, barrier.
    STAGE(0, 0);
    VM0();
    __builtin_amdgcn_s_barrier(); SCHEDB();

    // 32 K-tiles, unrolled in pairs so the buffer index is compile-time.
    for (int tt = 0; tt < 16; ++tt) {
        const int ktn0 = (2 * tt + 1) * BK;                  // stage tile 2tt+1
        int ktn1 = (2 * tt + 2) * BK;                        // stage tile 2tt+2
        if (ktn1 > KDIM - BK) ktn1 = KDIM - BK;              // clamp (harmless re-stage)
        KTILE(0, ktn0);
        KTILE(1, ktn1);
    }

    // Fused MSE epilogue. For tile (m,n): gr = rowBase+wrow+m*32+l31 (M),
    // reg 4Q+r -> gc = colBase+wcol+n*32+4*kh+8*Q+r (V, consecutive) -> float4.
    float sum = 0.f;
#pragma unroll
    for (int m = 0; m < 4; ++m) {
        const long gr = rowBase + wrow + m * 32 + l31;
        const float* yr = Y + gr * (long)VDIM + colBase + wcol + 4 * kh;
#pragma unroll
        for (int n = 0; n < 4; ++n) {
#pragma unroll
            for (int Q = 0; Q < 4; ++Q) {
                float4 yv = *(const float4*)(yr + n * 32 + 8 * Q);
                float d0 = acc[m][n][4 * Q + 0] - yv.x;
                float d1 = acc[m][n][4 * Q + 1] - yv.y;
                float d2 = acc[m][n][4 * Q + 2] - yv.z;
                float d3 = acc[m][n][4 * Q + 3] - yv.w;
                sum += d0 * d0 + d1 * d1 + d2 * d2 + d3 * d3;
            }
        }
    }
    sum += __shfl_down(sum, 32);
    sum += __shfl_down(sum, 16);
    sum += __shfl_down(sum, 8);
    sum += __shfl_down(sum, 4);
    sum += __shfl_down(sum, 2);
    sum += __shfl_down(sum, 1);
    float* red = (float*)(void*)As;       // safe: past final tile barrier
    if (lane == 0) red[wid] = sum;
    __syncthreads();
    if (tid == 0) {
        float t = (red[0] + red[1]) + (red[2] + red[3]);
        atomicAdd(out, t * (1.0f / ((float)MDIM * (float)VDIM)));
    }
}

extern "C" void kernel_launch(void* const* d_in, const int* in_sizes, int n_in,
                              void* d_out, int out_size, void* d_ws, size_t ws_size,
                              hipStream_t stream) {
    float* x = (float*)d_in[0];              // [2048, 2048]  (in-place cast)
    const float* y = (const float*)d_in[1];  // [2048, 32000]
    float* W = (float*)d_in[2];              // [32000, 2048] (in-place cast)
    float* out = (float*)d_out;
    (void)d_ws; (void)ws_size;

    cast_inplace_rows4_kernel<<<MDIM / 4, 256, 0, stream>>>(x, out);  // also zeroes out
    cast_inplace_rows4_kernel<<<VDIM / 4, 256, 0, stream>>>(W, nullptr);

    dim3 grid((MDIM / BM) * (VDIM / BN));  // 1000 blocks, swizzled in-kernel
    gemm_mse_kernel<<<grid, 256, 0, stream>>>(
        (const unsigned short*)x, (const unsigned short*)W, y, out);
}

// Round 4
// 750.005 us; speedup vs baseline: 1.1427x; 1.1427x over previous
//
#include <hip/hip_runtime.h>

// Problem constants (reference: N=2048, H=2048, V=32000)
#define MDIM 2048
#define KDIM 2048
#define VDIM 32000
#define BM 256
#define BN 256
#define BK 64
#define LDAB (2 * KDIM)  // bf16 row stride when casting in place into fp32 rows

typedef __bf16 bf16x8 __attribute__((ext_vector_type(8)));
typedef float f32x4 __attribute__((ext_vector_type(4)));

__device__ __forceinline__ unsigned short f32_to_bf16_rne(float f) {
    unsigned u = __float_as_uint(f);
    u += 0x7FFFu + ((u >> 16) & 1u);
    return (unsigned short)(u >> 16);
}

// Fused fp32 -> bf16 cast for BOTH x and W, 4 rows per block, one launch.
// DSTLD = dst row stride in shorts: KDIM (packed into d_ws, d_in untouched)
// or LDAB (in-place fallback; __syncthreads orders reads before writes).
template <int DSTLD>
__global__ __launch_bounds__(256) void cast_rows4_kernel(
        const float* __restrict__ xsrc, const float* __restrict__ wsrc,
        unsigned short* __restrict__ xdst, unsigned short* __restrict__ wdst,
        float* zero_out) {
    if (blockIdx.x == 0 && threadIdx.x == 0) *zero_out = 0.0f;
    const int nx = MDIM / 4;
    const float* src;
    unsigned short* dst;
    if (blockIdx.x < nx) {
        src = xsrc + (long)blockIdx.x * 4 * KDIM;
        dst = xdst + (long)blockIdx.x * 4 * DSTLD;
    } else {
        const int b = blockIdx.x - nx;
        src = wsrc + (long)b * 4 * KDIM;
        dst = wdst + (long)b * 4 * DSTLD;
    }
    const int t = threadIdx.x;
    float4 v[8];
#pragma unroll
    for (int rr = 0; rr < 4; ++rr) {
        const float4* p = reinterpret_cast<const float4*>(src + rr * KDIM + t * 8);
        v[2 * rr]     = p[0];
        v[2 * rr + 1] = p[1];
    }
    __syncthreads();   // in-place path: all reads of these rows before any write
#pragma unroll
    for (int rr = 0; rr < 4; ++rr) {
        union { unsigned short h[8]; uint4 u; } r;
        float4 a = v[2 * rr], b = v[2 * rr + 1];
        r.h[0] = f32_to_bf16_rne(a.x);
        r.h[1] = f32_to_bf16_rne(a.y);
        r.h[2] = f32_to_bf16_rne(a.z);
        r.h[3] = f32_to_bf16_rne(a.w);
        r.h[4] = f32_to_bf16_rne(b.x);
        r.h[5] = f32_to_bf16_rne(b.y);
        r.h[6] = f32_to_bf16_rne(b.z);
        r.h[7] = f32_to_bf16_rne(b.w);
        reinterpret_cast<uint4*>(dst + rr * DSTLD)[t] = r.u;
    }
}

// ---------------------------------------------------------------------------
// GEMM+MSE: identical to the verified round-2 kernel (302 us, MfmaUtil 38%,
// 0 bank conflicts) except the A/B row stride is a template param LDB.
// 256x256 tile, BK=64, 8-wave (2M x 4N), 8-phase schedule with counted vmcnt.
// LDS: As[2]+Bs[2] = 128 KiB dbuf. Per phase: {ds_read subtile, stage one
// half-tile, barrier, lgkmcnt(0), setprio(1), 16 MFMA, setprio(0), barrier}.
// vmcnt(4) ONLY at ph3/ph7. XOR seg-swizzle: row r stores global 16B-seg g
// at slot g ^ (r&7); readers XOR likewise (measured conflict-free).
// ---------------------------------------------------------------------------

#define BMFMA(a, b, c) __builtin_amdgcn_mfma_f32_16x16x32_bf16(a, b, c, 0, 0, 0)

#define GLL16(gp, lp) __builtin_amdgcn_global_load_lds( \
    (const __attribute__((address_space(1))) void*)(gp), \
    (__attribute__((address_space(3))) void*)(lp), 16, 0, 0)

#define STAGE_A(bi, hf, kt) do { \
    GLL16(aG0 + (size_t)(hf) * 128 * LDB + (kt), &As[bi][(hf) * 128 * BK + dOff0]); \
    GLL16(aG1 + (size_t)(hf) * 128 * LDB + (kt), &As[bi][(hf) * 128 * BK + dOff1]); \
} while (0)

#define STAGE_B(bi, hf, kt) do { \
    GLL16(bG0 + (size_t)(hf) * 128 * LDB + (kt), &Bs[bi][(hf) * 128 * BK + dOff0]); \
    GLL16(bG1 + (size_t)(hf) * 128 * LDB + (kt), &Bs[bi][(hf) * 128 * BK + dOff1]); \
} while (0)

#define DS_B1(bi, n) do { \
    const unsigned short* br_ = &Bs[bi][(wcol + (n) * 16 + m0) * BK]; \
    bfr[2 * (n)]     = *(const bf16x8*)(const void*)(br_ + off0); \
    bfr[2 * (n) + 1] = *(const bf16x8*)(const void*)(br_ + off1); \
} while (0)
#define DS_B8(bi) do { DS_B1(bi, 0); DS_B1(bi, 1); DS_B1(bi, 2); DS_B1(bi, 3); } while (0)

#define DS_A2(bi, mb) do { \
    const unsigned short* ar_ = &As[bi][(wrow + (mb) * 16 + m0) * BK]; \
    af[0] = *(const bf16x8*)(const void*)(ar_ + off0); \
    af[1] = *(const bf16x8*)(const void*)(ar_ + off1); \
    af[2] = *(const bf16x8*)(const void*)(ar_ + 16 * BK + off0); \
    af[3] = *(const bf16x8*)(const void*)(ar_ + 16 * BK + off1); \
} while (0)

#define MFMA16(mb) do { \
    acc[(mb)][0]     = BMFMA(af[0], bfr[0], acc[(mb)][0]); \
    acc[(mb) + 1][0] = BMFMA(af[2], bfr[0], acc[(mb) + 1][0]); \
    acc[(mb)][1]     = BMFMA(af[0], bfr[2], acc[(mb)][1]); \
    acc[(mb) + 1][1] = BMFMA(af[2], bfr[2], acc[(mb) + 1][1]); \
    acc[(mb)][2]     = BMFMA(af[0], bfr[4], acc[(mb)][2]); \
    acc[(mb) + 1][2] = BMFMA(af[2], bfr[4], acc[(mb) + 1][2]); \
    acc[(mb)][3]     = BMFMA(af[0], bfr[6], acc[(mb)][3]); \
    acc[(mb) + 1][3] = BMFMA(af[2], bfr[6], acc[(mb) + 1][3]); \
    acc[(mb)][0]     = BMFMA(af[1], bfr[1], acc[(mb)][0]); \
    acc[(mb) + 1][0] = BMFMA(af[3], bfr[1], acc[(mb) + 1][0]); \
    acc[(mb)][1]     = BMFMA(af[1], bfr[3], acc[(mb)][1]); \
    acc[(mb) + 1][1] = BMFMA(af[3], bfr[3], acc[(mb) + 1][1]); \
    acc[(mb)][2]     = BMFMA(af[1], bfr[5], acc[(mb)][2]); \
    acc[(mb) + 1][2] = BMFMA(af[3], bfr[5], acc[(mb) + 1][2]); \
    acc[(mb)][3]     = BMFMA(af[1], bfr[7], acc[(mb)][3]); \
    acc[(mb) + 1][3] = BMFMA(af[3], bfr[7], acc[(mb) + 1][3]); \
} while (0)

#define BAR() do { __builtin_amdgcn_s_barrier(); __builtin_amdgcn_sched_barrier(0); } while (0)
#define WAITKL() do { asm volatile("s_waitcnt lgkmcnt(0)" ::: "memory"); \
                      __builtin_amdgcn_sched_barrier(0); } while (0)
#define VMCNT4() do { asm volatile("s_waitcnt vmcnt(4)" ::: "memory"); \
                      __builtin_amdgcn_sched_barrier(0); } while (0)
#define VMCNT0() do { asm volatile("s_waitcnt vmcnt(0)" ::: "memory"); \
                      __builtin_amdgcn_sched_barrier(0); } while (0)

#define PHASE(dsr, stg, wt, bi, mb) do { \
    dsr; stg; wt; \
    BAR(); WAITKL(); \
    __builtin_amdgcn_s_setprio(1); \
    MFMA16(mb); \
    __builtin_amdgcn_s_setprio(0); \
    BAR(); \
} while (0)

template <int LDB>
__global__ __launch_bounds__(512, 2) void gemm_mse_kernel(
        const unsigned short* __restrict__ A,  // x as bf16, stride LDB
        const unsigned short* __restrict__ B,  // W as bf16, stride LDB
        const float* __restrict__ Y,           // [MDIM,VDIM] fp32
        float* __restrict__ out) {
    __shared__ __align__(16) unsigned short As[2][BM * BK];  // 64 KB
    __shared__ __align__(16) unsigned short Bs[2][BN * BK];  // 64 KB

    const int tid  = threadIdx.x;
    const int lane = tid & 63;
    const int wid  = tid >> 6;            // 0..7
    const int wrow = (wid >> 2) * 128;    // wave M offset in tile
    const int wcol = (wid & 3) * 64;      // wave V offset in tile
    const int m0 = lane & 15;
    const int q  = lane >> 4;             // 0..3

    // XCD-aware bijective swizzle: 1000 blocks, 1000 % 8 == 0.
    const int lin = blockIdx.x;
    const int swz = (lin & 7) * 125 + (lin >> 3);
    const int tm = swz & 7;               // 8 M tiles (fast)
    const int tv = swz >> 3;              // 125 V tiles (slow)
    const long rowBase = (long)tm * BM;
    const long colBase = (long)tv * BN;

    f32x4 acc[8][4];
#pragma unroll
    for (int i = 0; i < 8; ++i)
#pragma unroll
        for (int j = 0; j < 4; ++j)
            acc[i][j] = (f32x4){0.f, 0.f, 0.f, 0.f};

    // Staging: half-tile = 128 rows x 64 bf16 = 1024 x 16B slots; 512 thr x 2.
    // Slot l: row=l>>3, stored seg=l&7, global seg=(l&7)^(row&7). LDS dest
    // linear (wave-uniform + lane*16); swizzle lives in the global src addr.
    const int l0 = tid, l1 = tid + 512;
    const int r0 = l0 >> 3, r1 = l1 >> 3;
    const int g0 = (l0 & 7) ^ (r0 & 7), g1 = (l1 & 7) ^ (r1 & 7);
    const unsigned short* aG0 = A + (size_t)(rowBase + r0) * LDB + g0 * 8;
    const unsigned short* aG1 = A + (size_t)(rowBase + r1) * LDB + g1 * 8;
    const unsigned short* bG0 = B + (size_t)(colBase + r0) * LDB + g0 * 8;
    const unsigned short* bG1 = B + (size_t)(colBase + r1) * LDB + g1 * 8;
    const int dOff0 = l0 * 8, dOff1 = l1 * 8;

    // Fragment read offsets: global seg (h*4+q) stored at (h*4+q)^(row&7);
    // row&7 == m0&7 (wrow, mb*16 are multiples of 8).
    const int sxor = m0 & 7;
    const int off0 = ((0 + q) ^ sxor) * 8;
    const int off1 = ((4 + q) ^ sxor) * 8;

    bf16x8 af[4];   // A frags: current m-pair x 2 k-halves
    bf16x8 bfr[8];  // B frags: 4 n x 2 k-halves, resident per K-tile

    // Prologue: T0 full (8 loads) + T1.B (4 loads); vmcnt(4) => T0 landed.
    STAGE_A(0, 0, 0); STAGE_A(0, 1, 0);
    STAGE_B(0, 0, 0); STAGE_B(0, 1, 0);
    STAGE_B(1, 0, BK); STAGE_B(1, 1, BK);
    VMCNT4();
    BAR();

    for (int i = 0; i < 16; ++i) {
        const int ktb  = i * 2 * BK;
        const int ktA1 = ktb + BK;
        int ktN  = ktb + 2 * BK;
        if (ktN  > KDIM - BK) ktN  = KDIM - BK;   // clamp: harmless re-stage
        int ktN1 = ktb + 3 * BK;
        if (ktN1 > KDIM - BK) ktN1 = KDIM - BK;

        // ph0..ph3: compute tile 2i from buf0
        PHASE({ DS_B8(0); DS_A2(0, 0); },
              { STAGE_A(1, 0, ktA1); STAGE_A(1, 1, ktA1); }, , 0, 0);
        PHASE(DS_A2(0, 2), STAGE_B(0, 0, ktN), , 0, 2);
        PHASE(DS_A2(0, 4), STAGE_B(0, 1, ktN), , 0, 4);
        PHASE(DS_A2(0, 6), , VMCNT4(), 0, 6);
        // ph4..ph7: compute tile 2i+1 from buf1
        PHASE({ DS_B8(1); DS_A2(1, 0); }, STAGE_A(0, 0, ktN), , 1, 0);
        PHASE(DS_A2(1, 2), STAGE_A(0, 1, ktN), , 1, 2);
        PHASE(DS_A2(1, 4), STAGE_B(1, 0, ktN1), , 1, 4);
        PHASE(DS_A2(1, 6), STAGE_B(1, 1, ktN1), VMCNT4(), 1, 6);
    }

    VMCNT0();  // drain clamped tail stages before reusing LDS
    BAR();

    // Fused MSE epilogue. C/D layout: col = lane&15, row = (lane>>4)*4 + reg.
    float sum = 0.f;
#pragma unroll
    for (int m = 0; m < 8; ++m) {
#pragma unroll
        for (int n = 0; n < 4; ++n) {
            long gr = rowBase + wrow + m * 16 + q * 4;
            long gc = colBase + wcol + n * 16 + m0;
            const float* yp = Y + gr * (long)VDIM + gc;
#pragma unroll
            for (int r = 0; r < 4; ++r) {
                float d = acc[m][n][r] - yp[(long)r * VDIM];
                sum += d * d;
            }
        }
    }
    sum += __shfl_down(sum, 32);
    sum += __shfl_down(sum, 16);
    sum += __shfl_down(sum, 8);
    sum += __shfl_down(sum, 4);
    sum += __shfl_down(sum, 2);
    sum += __shfl_down(sum, 1);
    float* red = (float*)(void*)As;
    if (lane == 0) red[wid] = sum;
    __syncthreads();
    if (tid == 0) {
        float t = 0.f;
#pragma unroll
        for (int w = 0; w < 8; ++w) t += red[w];
        atomicAdd(out, t * (1.0f / ((float)MDIM * (float)VDIM)));
    }
}

extern "C" void kernel_launch(void* const* d_in, const int* in_sizes, int n_in,
                              void* d_out, int out_size, void* d_ws, size_t ws_size,
                              hipStream_t stream) {
    float* x = (float*)d_in[0];              // [2048, 2048]  fp32
    const float* y = (const float*)d_in[1];  // [2048, 32000] fp32
    float* W = (float*)d_in[2];              // [32000, 2048] fp32
    float* out = (float*)d_out;

    const size_t need = ((size_t)MDIM + (size_t)VDIM) * KDIM * sizeof(unsigned short);
    dim3 grid((MDIM / BM) * (VDIM / BN));  // 1000 blocks, swizzled in-kernel
    const int castBlocks = (MDIM + VDIM) / 4;  // 8512

    if (d_ws != nullptr && ws_size >= need) {
        // Packed-bf16 path: d_in stays pristine (no per-iter restore needed).
        unsigned short* xb = (unsigned short*)d_ws;
        unsigned short* wb = xb + (size_t)MDIM * KDIM;
        cast_rows4_kernel<KDIM><<<castBlocks, 256, 0, stream>>>(x, W, xb, wb, out);
        gemm_mse_kernel<KDIM><<<grid, 512, 0, stream>>>(xb, wb, y, out);
    } else {
        // Fallback: verified in-place path (identical to round-2 behavior).
        cast_rows4_kernel<LDAB><<<castBlocks, 256, 0, stream>>>(
            x, W, (unsigned short*)x, (unsigned short*)W, out);
        gemm_mse_kernel<LDAB><<<grid, 512, 0, stream>>>(
            (const unsigned short*)x, (const unsigned short*)W, y, out);
    }
}